// Round 1
// baseline (1027.603 us; speedup 1.0000x reference)
//
#include <hip/hip_runtime.h>
#include <hip/hip_bf16.h>
#include <math.h>

// Problem constants
#define NI 20000
#define DC 768
#define DT 384
#define DD 64
#define NROWS 51200   // B*T = 512*100

// ---------------- row inverse-norm (for F.normalize of raw features) -------
__global__ __launch_bounds__(256) void rownorm_kernel(
    const float* __restrict__ X, float* __restrict__ inv, int M, int K) {
  int row = blockIdx.x * 4 + (threadIdx.x >> 6);
  int lane = threadIdx.x & 63;
  if (row >= M) return;
  const float* x = X + (size_t)row * K;
  float s = 0.f;
  int K4 = K >> 2;
  for (int k4 = lane; k4 < K4; k4 += 64) {
    float4 v = *(const float4*)(x + k4 * 4);
    s += v.x * v.x + v.y * v.y + v.z * v.z + v.w * v.w;
  }
#pragma unroll
  for (int off = 32; off; off >>= 1) s += __shfl_xor(s, off);
  if (lane == 0) inv[row] = 1.0f / fmaxf(sqrtf(s), 1e-12f);
}

// ---------------- generic f32 GEMM: C = act(A @ B^T + bias) ----------------
// A [M,K] row-major (optional per-row scale), B [N,K] row-major, C [M,N]
#define BM 128
#define BN 64
#define BK 16

template <int RELU, int SCALEA>
__global__ __launch_bounds__(256) void gemm_kernel(
    const float* __restrict__ A, const float* __restrict__ Bw,
    const float* __restrict__ bias, const float* __restrict__ scaleA,
    float* __restrict__ C, int M, int N, int K) {
  __shared__ float As[BK][BM + 4];
  __shared__ float Bs[BK][BN + 4];
  const int tid = threadIdx.x;
  const int tx = tid & 15, ty = tid >> 4;
  const int row0 = blockIdx.x * BM;
  const int col0 = blockIdx.y * BN;
  float acc[8][4] = {};

  for (int k0 = 0; k0 < K; k0 += BK) {
#pragma unroll
    for (int i = 0; i < 2; ++i) {   // A tile: 128x16 = 512 float4
      int idx = tid + i * 256;
      int m = idx >> 2, kq = idx & 3;
      int gr = row0 + m;
      float4 a = make_float4(0.f, 0.f, 0.f, 0.f);
      if (gr < M) {
        a = *(const float4*)(A + (size_t)gr * K + k0 + kq * 4);
        if (SCALEA) {
          float s = scaleA[gr];
          a.x *= s; a.y *= s; a.z *= s; a.w *= s;
        }
      }
      As[kq * 4 + 0][m] = a.x; As[kq * 4 + 1][m] = a.y;
      As[kq * 4 + 2][m] = a.z; As[kq * 4 + 3][m] = a.w;
    }
    {                               // B tile: 64x16 = 256 float4
      int n = tid >> 2, kq = tid & 3;
      float4 b = *(const float4*)(Bw + (size_t)(col0 + n) * K + k0 + kq * 4);
      Bs[kq * 4 + 0][n] = b.x; Bs[kq * 4 + 1][n] = b.y;
      Bs[kq * 4 + 2][n] = b.z; Bs[kq * 4 + 3][n] = b.w;
    }
    __syncthreads();
#pragma unroll
    for (int kk = 0; kk < BK; ++kk) {
      float av[8], bv[4];
      *(float4*)&av[0] = *(const float4*)&As[kk][ty * 8];
      *(float4*)&av[4] = *(const float4*)&As[kk][ty * 8 + 4];
      *(float4*)&bv[0] = *(const float4*)&Bs[kk][tx * 4];
#pragma unroll
      for (int i = 0; i < 8; ++i)
#pragma unroll
        for (int j = 0; j < 4; ++j) acc[i][j] = fmaf(av[i], bv[j], acc[i][j]);
    }
    __syncthreads();
  }

  float4 bb = *(const float4*)(bias + col0 + tx * 4);
#pragma unroll
  for (int i = 0; i < 8; ++i) {
    int m = row0 + ty * 8 + i;
    if (m < M) {
      float4 o;
      o.x = acc[i][0] + bb.x; o.y = acc[i][1] + bb.y;
      o.z = acc[i][2] + bb.z; o.w = acc[i][3] + bb.w;
      if (RELU) {
        o.x = fmaxf(o.x, 0.f); o.y = fmaxf(o.y, 0.f);
        o.z = fmaxf(o.z, 0.f); o.w = fmaxf(o.w, 0.f);
      }
      *(float4*)(C + (size_t)m * N + col0 + tx * 4) = o;
    }
  }
}

// ---------------- layer-3 GEMM with fused row-l2 epilogue (N == 64) --------
// mm = l2(A @ B^T + bias)   (ACCUM: mm += ...)
template <int ACCUM>
__global__ __launch_bounds__(256) void gemm_l2_kernel(
    const float* __restrict__ A, const float* __restrict__ Bw,
    const float* __restrict__ bias, float* __restrict__ Cmm, int M, int K) {
  __shared__ float As[BK][BM + 4];
  __shared__ float Bs[BK][BN + 4];
  __shared__ float sq[BM][16];
  const int tid = threadIdx.x;
  const int tx = tid & 15, ty = tid >> 4;
  const int row0 = blockIdx.x * BM;
  float acc[8][4] = {};

  for (int k0 = 0; k0 < K; k0 += BK) {
#pragma unroll
    for (int i = 0; i < 2; ++i) {
      int idx = tid + i * 256;
      int m = idx >> 2, kq = idx & 3;
      int gr = row0 + m;
      float4 a = make_float4(0.f, 0.f, 0.f, 0.f);
      if (gr < M) a = *(const float4*)(A + (size_t)gr * K + k0 + kq * 4);
      As[kq * 4 + 0][m] = a.x; As[kq * 4 + 1][m] = a.y;
      As[kq * 4 + 2][m] = a.z; As[kq * 4 + 3][m] = a.w;
    }
    {
      int n = tid >> 2, kq = tid & 3;
      float4 b = *(const float4*)(Bw + (size_t)n * K + k0 + kq * 4);
      Bs[kq * 4 + 0][n] = b.x; Bs[kq * 4 + 1][n] = b.y;
      Bs[kq * 4 + 2][n] = b.z; Bs[kq * 4 + 3][n] = b.w;
    }
    __syncthreads();
#pragma unroll
    for (int kk = 0; kk < BK; ++kk) {
      float av[8], bv[4];
      *(float4*)&av[0] = *(const float4*)&As[kk][ty * 8];
      *(float4*)&av[4] = *(const float4*)&As[kk][ty * 8 + 4];
      *(float4*)&bv[0] = *(const float4*)&Bs[kk][tx * 4];
#pragma unroll
      for (int i = 0; i < 8; ++i)
#pragma unroll
        for (int j = 0; j < 4; ++j) acc[i][j] = fmaf(av[i], bv[j], acc[i][j]);
    }
    __syncthreads();
  }

  float4 bb = *(const float4*)(bias + tx * 4);
  float vals[8][4];
#pragma unroll
  for (int i = 0; i < 8; ++i) {
    vals[i][0] = acc[i][0] + bb.x; vals[i][1] = acc[i][1] + bb.y;
    vals[i][2] = acc[i][2] + bb.z; vals[i][3] = acc[i][3] + bb.w;
    sq[ty * 8 + i][tx] = vals[i][0] * vals[i][0] + vals[i][1] * vals[i][1] +
                         vals[i][2] * vals[i][2] + vals[i][3] * vals[i][3];
  }
  __syncthreads();
#pragma unroll
  for (int i = 0; i < 8; ++i) {
    int m = row0 + ty * 8 + i;
    if (m < M) {
      float s = 0.f;
#pragma unroll
      for (int t = 0; t < 16; ++t) s += sq[ty * 8 + i][t];
      float inv = 1.0f / fmaxf(sqrtf(s), 1e-12f);
      float4 o;
      o.x = vals[i][0] * inv; o.y = vals[i][1] * inv;
      o.z = vals[i][2] * inv; o.w = vals[i][3] * inv;
      if (ACCUM) {
        float4 p = *(const float4*)(Cmm + (size_t)m * 64 + tx * 4);
        o.x += p.x; o.y += p.y; o.z += p.z; o.w += p.w;
      }
      *(float4*)(Cmm + (size_t)m * 64 + tx * 4) = o;
    }
  }
}

// ---------------- cf linear with cold-mask select (N == K == 64) -----------
__global__ __launch_bounds__(256) void gemm_cf_kernel(
    const float* __restrict__ A, const float* __restrict__ Bw,
    const float* __restrict__ bias, const int* __restrict__ cold,
    const float* __restrict__ mmf, float* __restrict__ C, int M) {
  __shared__ float As[BK][BM + 4];
  __shared__ float Bs[BK][BN + 4];
  const int tid = threadIdx.x;
  const int tx = tid & 15, ty = tid >> 4;
  const int row0 = blockIdx.x * BM;
  const int K = 64;
  float acc[8][4] = {};

  for (int k0 = 0; k0 < K; k0 += BK) {
#pragma unroll
    for (int i = 0; i < 2; ++i) {
      int idx = tid + i * 256;
      int m = idx >> 2, kq = idx & 3;
      int gr = row0 + m;
      float4 a = make_float4(0.f, 0.f, 0.f, 0.f);
      if (gr < M) a = *(const float4*)(A + (size_t)gr * K + k0 + kq * 4);
      As[kq * 4 + 0][m] = a.x; As[kq * 4 + 1][m] = a.y;
      As[kq * 4 + 2][m] = a.z; As[kq * 4 + 3][m] = a.w;
    }
    {
      int n = tid >> 2, kq = tid & 3;
      float4 b = *(const float4*)(Bw + (size_t)n * K + k0 + kq * 4);
      Bs[kq * 4 + 0][n] = b.x; Bs[kq * 4 + 1][n] = b.y;
      Bs[kq * 4 + 2][n] = b.z; Bs[kq * 4 + 3][n] = b.w;
    }
    __syncthreads();
#pragma unroll
    for (int kk = 0; kk < BK; ++kk) {
      float av[8], bv[4];
      *(float4*)&av[0] = *(const float4*)&As[kk][ty * 8];
      *(float4*)&av[4] = *(const float4*)&As[kk][ty * 8 + 4];
      *(float4*)&bv[0] = *(const float4*)&Bs[kk][tx * 4];
#pragma unroll
      for (int i = 0; i < 8; ++i)
#pragma unroll
        for (int j = 0; j < 4; ++j) acc[i][j] = fmaf(av[i], bv[j], acc[i][j]);
    }
    __syncthreads();
  }

  float4 bb = *(const float4*)(bias + tx * 4);
#pragma unroll
  for (int i = 0; i < 8; ++i) {
    int m = row0 + ty * 8 + i;
    if (m < M) {
      float4 o;
      o.x = acc[i][0] + bb.x; o.y = acc[i][1] + bb.y;
      o.z = acc[i][2] + bb.z; o.w = acc[i][3] + bb.w;
      if (cold[m] > 0) o = *(const float4*)(mmf + (size_t)m * 64 + tx * 4);
      *(float4*)(C + (size_t)m * 64 + tx * 4) = o;
    }
  }
}

// ---------------- fused gather / l2 / LN / qkv / attention / mean ----------
// One wave per output row; 4 waves per block, 4 rows per wave => 16 rows/block.
__global__ __launch_bounds__(256) void attn_kernel(
    const int* __restrict__ seq, const float* __restrict__ mmf,
    const float* __restrict__ ie, const float* __restrict__ cf,
    const float* __restrict__ wq, const float* __restrict__ wk,
    const float* __restrict__ wv, float* __restrict__ out) {
  __shared__ float wql[64 * 64];   // transposed: [d][j]
  __shared__ float wkl[64 * 64];
  __shared__ float wvl[64 * 64];
  __shared__ float xnl[4][3][64];
  __shared__ float zl[4][64];
  const int tid = threadIdx.x;
  for (int idx = tid; idx < 4096; idx += 256) {
    int j = idx >> 6, d = idx & 63;
    wql[d * 64 + j] = wq[idx];
    wkl[d * 64 + j] = wk[idx];
    wvl[d * 64 + j] = wv[idx];
  }
  __syncthreads();
  const int w = tid >> 6, lane = tid & 63;
  const int rowBase = blockIdx.x * 16;

  for (int rr = 0; rr < 4; ++rr) {
    const int row = rowBase + rr * 4 + w;
    int sidx = seq[row];
    sidx = (sidx == NI) ? 0 : sidx;
    const size_t base = (size_t)sidx * 64 + lane;
    float fv[3];
    fv[0] = mmf[base]; fv[1] = ie[base]; fv[2] = cf[base];
    float xr[3];
#pragma unroll
    for (int t = 0; t < 3; ++t) {
      float v = fv[t];
      float s1 = v, s2 = v * v;
#pragma unroll
      for (int off = 32; off; off >>= 1) {
        s1 += __shfl_xor(s1, off);
        s2 += __shfl_xor(s2, off);
      }
      // l2 (F.normalize, eps 1e-12) then LayerNorm (eps 1e-5, no affine)
      float inv = 1.0f / fmaxf(sqrtf(s2), 1e-12f);
      float x = v * inv;
      float mu = s1 * inv * 0.015625f;
      float var = fmaxf(s2 * inv * inv * 0.015625f - mu * mu, 0.0f);
      float rs = 1.0f / sqrtf(var + 1e-5f);
      float xn = (x - mu) * rs;
      xr[t] = xn;
      xnl[w][t][lane] = xn;
    }
    __syncthreads();

    // q[t][lane], k[t][lane]
    float q0 = 0, q1 = 0, q2 = 0, k0 = 0, k1 = 0, k2 = 0;
#pragma unroll 4
    for (int d0 = 0; d0 < 64; d0 += 4) {
      float xa[4], xb[4], xc[4];
      *(float4*)xa = *(const float4*)&xnl[w][0][d0];
      *(float4*)xb = *(const float4*)&xnl[w][1][d0];
      *(float4*)xc = *(const float4*)&xnl[w][2][d0];
#pragma unroll
      for (int i = 0; i < 4; ++i) {
        const int d = d0 + i;
        float a = wql[d * 64 + lane];
        float b = wkl[d * 64 + lane];
        q0 = fmaf(xa[i], a, q0); q1 = fmaf(xb[i], a, q1); q2 = fmaf(xc[i], a, q2);
        k0 = fmaf(xa[i], b, k0); k1 = fmaf(xb[i], b, k1); k2 = fmaf(xc[i], b, k2);
      }
    }
    float qv[3] = {q0, q1, q2}, kv[3] = {k0, k1, k2};
    float lg[3][3];
#pragma unroll
    for (int a = 0; a < 3; ++a)
#pragma unroll
      for (int b = 0; b < 3; ++b) {
        float s = qv[a] * kv[b];
#pragma unroll
        for (int off = 32; off; off >>= 1) s += __shfl_xor(s, off);
        lg[a][b] = s * 0.125f;   // D^-0.5 = 1/8
      }
    float coef0 = 0, coef1 = 0, coef2 = 0;
#pragma unroll
    for (int a = 0; a < 3; ++a) {
      float mx = fmaxf(lg[a][0], fmaxf(lg[a][1], lg[a][2]));
      float e0 = expf(lg[a][0] - mx);
      float e1 = expf(lg[a][1] - mx);
      float e2 = expf(lg[a][2] - mx);
      float is = 1.0f / (e0 + e1 + e2);
      coef0 += e0 * is; coef1 += e1 * is; coef2 += e2 * is;
    }
    // y = W_v @ (sum_b coef_b * xn_b) / 3
    float z = (coef0 * xr[0] + coef1 * xr[1] + coef2 * xr[2]) * (1.0f / 3.0f);
    zl[w][lane] = z;
    __syncthreads();
    float y = 0.f;
#pragma unroll 4
    for (int d0 = 0; d0 < 64; d0 += 4) {
      float za[4];
      *(float4*)za = *(const float4*)&zl[w][d0];
#pragma unroll
      for (int i = 0; i < 4; ++i) y = fmaf(za[i], wvl[(d0 + i) * 64 + lane], y);
    }
    out[(size_t)row * 64 + lane] = y;
    __syncthreads();
  }
}

extern "C" void kernel_launch(void* const* d_in, const int* in_sizes, int n_in,
                              void* d_out, int out_size, void* d_ws, size_t ws_size,
                              hipStream_t stream) {
  const int*   seq     = (const int*)d_in[0];
  const int*   cold    = (const int*)d_in[1];
  const float* content = (const float*)d_in[2];
  const float* text    = (const float*)d_in[3];
  const float* cff     = (const float*)d_in[4];
  const float* iemb    = (const float*)d_in[5];
  const float* c_w1 = (const float*)d_in[6];
  const float* c_b1 = (const float*)d_in[7];
  const float* c_w2 = (const float*)d_in[8];
  const float* c_b2 = (const float*)d_in[9];
  const float* c_w3 = (const float*)d_in[10];
  const float* c_b3 = (const float*)d_in[11];
  const float* t_w1 = (const float*)d_in[12];
  const float* t_b1 = (const float*)d_in[13];
  const float* t_w2 = (const float*)d_in[14];
  const float* t_b2 = (const float*)d_in[15];
  const float* t_w3 = (const float*)d_in[16];
  const float* t_b3 = (const float*)d_in[17];
  const float* cf_w = (const float*)d_in[18];
  const float* cf_b = (const float*)d_in[19];
  const float* w_q  = (const float*)d_in[20];
  const float* w_k  = (const float*)d_in[21];
  const float* w_v  = (const float*)d_in[22];
  float* out = (float*)d_out;

  float* ws   = (float*)d_ws;
  float* H1   = ws;                    // 20000*768
  float* H2   = H1 + 15360000;         // 20000*256
  float* mmf  = H2 + 5120000;          // 20000*64
  float* cfo  = mmf + 1280000;         // 20000*64
  float* invc = cfo + 1280000;         // 20000
  float* invt = invc + 20000;          // 20000

  rownorm_kernel<<<5000, 256, 0, stream>>>(content, invc, NI, DC);
  rownorm_kernel<<<5000, 256, 0, stream>>>(text, invt, NI, DT);

  // content encoder
  gemm_kernel<1, 1><<<dim3(157, 12), 256, 0, stream>>>(content, c_w1, c_b1, invc, H1, NI, DC, DC);
  gemm_kernel<1, 0><<<dim3(157, 4), 256, 0, stream>>>(H1, c_w2, c_b2, nullptr, H2, NI, 256, DC);
  gemm_l2_kernel<0><<<dim3(157), 256, 0, stream>>>(H2, c_w3, c_b3, mmf, NI, 256);

  // text encoder
  gemm_kernel<1, 1><<<dim3(157, 6), 256, 0, stream>>>(text, t_w1, t_b1, invt, H1, NI, DT, DT);
  gemm_kernel<1, 0><<<dim3(157, 4), 256, 0, stream>>>(H1, t_w2, t_b2, nullptr, H2, NI, 256, DT);
  gemm_l2_kernel<1><<<dim3(157), 256, 0, stream>>>(H2, t_w3, t_b3, mmf, NI, 256);

  // cf linear + cold-item scatter
  gemm_cf_kernel<<<dim3(157), 256, 0, stream>>>(cff, cf_w, cf_b, cold, mmf, cfo, NI);

  // gather + l2 + LN + qkv + 3x3 attention + mean
  attn_kernel<<<3200, 256, 0, stream>>>(seq, mmf, iemb, cfo, w_q, w_k, w_v, out);
}

// Round 2
// 788.456 us; speedup vs baseline: 1.3033x; 1.3033x over previous
//
#include <hip/hip_runtime.h>
#include <hip/hip_bf16.h>
#include <math.h>

// Problem constants
#define NI 20000
#define MPAD 20096   // 157 * 128

typedef _Float16 f16;
typedef _Float16 f16x8 __attribute__((ext_vector_type(8)));
typedef _Float16 f16x4 __attribute__((ext_vector_type(4)));
typedef float f32x4 __attribute__((ext_vector_type(4)));

// ---------------- l2-normalize rows + convert to fp16 (pad rows zeroed) ----
template <int K>
__global__ __launch_bounds__(256) void l2cvt_kernel(
    const float* __restrict__ X, f16* __restrict__ Y) {
  int row = blockIdx.x * 4 + (threadIdx.x >> 6);
  int lane = threadIdx.x & 63;
  if (row >= MPAD) return;
  f16* y = Y + (size_t)row * K;
  if (row >= NI) {
    for (int k4 = lane; k4 < K / 4; k4 += 64)
      *(uint2*)(y + k4 * 4) = make_uint2(0u, 0u);
    return;
  }
  const float* x = X + (size_t)row * K;
  float s = 0.f;
  for (int k4 = lane; k4 < K / 4; k4 += 64) {
    float4 v = *(const float4*)(x + k4 * 4);
    s += v.x * v.x + v.y * v.y + v.z * v.z + v.w * v.w;
  }
#pragma unroll
  for (int off = 32; off; off >>= 1) s += __shfl_xor(s, off);
  float inv = 1.0f / fmaxf(sqrtf(s), 1e-12f);
  for (int k4 = lane; k4 < K / 4; k4 += 64) {
    float4 v = *(const float4*)(x + k4 * 4);   // L1/L2 hit
    f16x4 h;
    h[0] = (f16)(v.x * inv); h[1] = (f16)(v.y * inv);
    h[2] = (f16)(v.z * inv); h[3] = (f16)(v.w * inv);
    *(f16x4*)(y + k4 * 4) = h;
  }
}

// ---------------- f32 -> fp16 elementwise (weights) ------------------------
__global__ __launch_bounds__(256) void cvt_kernel(
    const float* __restrict__ src, f16* __restrict__ dst, int n4) {
  int i = blockIdx.x * 256 + threadIdx.x;
  if (i < n4) {
    float4 v = *(const float4*)(src + (size_t)i * 4);
    f16x4 h;
    h[0] = (f16)v.x; h[1] = (f16)v.y; h[2] = (f16)v.z; h[3] = (f16)v.w;
    *(f16x4*)(dst + (size_t)i * 4) = h;
  }
}

// ---------------- MFMA fp16 GEMM: C = act(A @ B^T + bias) ------------------
// A [MPAD][K] fp16 row-major, B [N][K] fp16 row-major, bias f32 [N].
// Tile 128x64, BK=64, 256 threads = 4 waves (2x2), wave sub-tile 64x32.
// LDS row-major tiles with XOR swizzle: byte ^= ((row&7)<<4)  (T2).
template <int K, int N, int RELU, int OUTF16>
__global__ __launch_bounds__(256) void mgemm_kernel(
    const f16* __restrict__ A, const f16* __restrict__ B,
    const float* __restrict__ bias, void* Cout) {
  __shared__ __align__(16) char AsB[16384];   // 128 rows x 128 B
  __shared__ __align__(16) char BsB[8192];    // 64 rows x 128 B
  const int tid = threadIdx.x;
  const int l = tid & 63;
  const int w = tid >> 6;
  const int wr = w >> 1, wc = w & 1;
  const int row0 = blockIdx.x * 128;
  const int col0 = blockIdx.y * 64;
  constexpr int KT = K / 64;

  f32x4 acc[4][2];
  const f32x4 fz = {0.f, 0.f, 0.f, 0.f};
#pragma unroll
  for (int m = 0; m < 4; ++m)
#pragma unroll
    for (int n = 0; n < 2; ++n) acc[m][n] = fz;

  uint4 ra[4], rb[2];

  auto LOAD = [&](int kt) {
#pragma unroll
    for (int i = 0; i < 4; ++i) {
      int idx = i * 256 + tid;
      int r = idx >> 3, c8 = (idx & 7) * 8;
      ra[i] = *(const uint4*)(A + (size_t)(row0 + r) * K + kt * 64 + c8);
    }
#pragma unroll
    for (int i = 0; i < 2; ++i) {
      int idx = i * 256 + tid;
      int r = idx >> 3, c8 = (idx & 7) * 8;
      rb[i] = *(const uint4*)(B + (size_t)(col0 + r) * K + kt * 64 + c8);
    }
  };
  auto STORE_LDS = [&]() {
#pragma unroll
    for (int i = 0; i < 4; ++i) {
      int idx = i * 256 + tid;
      int r = idx >> 3, cb = (idx & 7) * 16;
      *(uint4*)(AsB + r * 128 + (cb ^ ((r & 7) << 4))) = ra[i];
    }
#pragma unroll
    for (int i = 0; i < 2; ++i) {
      int idx = i * 256 + tid;
      int r = idx >> 3, cb = (idx & 7) * 16;
      *(uint4*)(BsB + r * 128 + (cb ^ ((r & 7) << 4))) = rb[i];
    }
  };

  const int g = l >> 4, s = l & 7;
  const int aBase = (wr * 64 + (l & 15)) * 128;
  const int bBase = (wc * 32 + (l & 15)) * 128;

  auto COMPUTE = [&]() {
#pragma unroll
    for (int ks = 0; ks < 2; ++ks) {
      const int sw = ((((ks << 2) | g) ^ s) << 4);
      f16x8 af[4], bf[2];
#pragma unroll
      for (int m = 0; m < 4; ++m)
        af[m] = *(const f16x8*)(AsB + aBase + m * 2048 + sw);
#pragma unroll
      for (int n = 0; n < 2; ++n)
        bf[n] = *(const f16x8*)(BsB + bBase + n * 2048 + sw);
#pragma unroll
      for (int m = 0; m < 4; ++m)
#pragma unroll
        for (int n = 0; n < 2; ++n)
          acc[m][n] = __builtin_amdgcn_mfma_f32_16x16x32_f16(af[m], bf[n], acc[m][n], 0, 0, 0);
    }
  };

  LOAD(0);
#pragma unroll
  for (int kt = 0; kt < KT; ++kt) {
    if (kt) __syncthreads();
    STORE_LDS();
    __syncthreads();
    if (kt + 1 < KT) LOAD(kt + 1);
    COMPUTE();
  }

  // epilogue
  const float bn0 = bias[col0 + wc * 32 + (l & 15)];
  const float bn1 = bias[col0 + wc * 32 + 16 + (l & 15)];
#pragma unroll
  for (int m = 0; m < 4; ++m) {
#pragma unroll
    for (int n = 0; n < 2; ++n) {
      const float bb = n ? bn1 : bn0;
      const int col = col0 + wc * 32 + n * 16 + (l & 15);
#pragma unroll
      for (int r = 0; r < 4; ++r) {
        const int row = row0 + wr * 64 + m * 16 + (l >> 4) * 4 + r;
        float o = acc[m][n][r] + bb;
        if (RELU) o = fmaxf(o, 0.f);
        if (OUTF16) ((f16*)Cout)[(size_t)row * N + col] = (f16)o;
        else        ((float*)Cout)[(size_t)row * N + col] = o;
      }
    }
  }
}

// ---------------- mm = l2(C3c) + l2(C3t), rows < NI ------------------------
__global__ __launch_bounds__(256) void l2add_kernel(
    const float* __restrict__ Xc, const float* __restrict__ Xt,
    float* __restrict__ mmf) {
  int row = blockIdx.x * 4 + (threadIdx.x >> 6);
  int l = threadIdx.x & 63;
  if (row >= NI) return;
  float a = Xc[(size_t)row * 64 + l];
  float b = Xt[(size_t)row * 64 + l];
  float sa = a * a, sb = b * b;
#pragma unroll
  for (int off = 32; off; off >>= 1) {
    sa += __shfl_xor(sa, off);
    sb += __shfl_xor(sb, off);
  }
  float ia = 1.0f / fmaxf(sqrtf(sa), 1e-12f);
  float ib = 1.0f / fmaxf(sqrtf(sb), 1e-12f);
  mmf[(size_t)row * 64 + l] = a * ia + b * ib;
}

// ---------------- cf linear with cold-mask select (f32, N == K == 64) ------
#define BM 128
#define BK 16
__global__ __launch_bounds__(256) void gemm_cf_kernel(
    const float* __restrict__ A, const float* __restrict__ Bw,
    const float* __restrict__ bias, const int* __restrict__ cold,
    const float* __restrict__ mmf, float* __restrict__ C, int M) {
  __shared__ float As[BK][BM + 4];
  __shared__ float Bs[BK][64 + 4];
  const int tid = threadIdx.x;
  const int tx = tid & 15, ty = tid >> 4;
  const int row0 = blockIdx.x * BM;
  const int K = 64;
  float acc[8][4] = {};

  for (int k0 = 0; k0 < K; k0 += BK) {
#pragma unroll
    for (int i = 0; i < 2; ++i) {
      int idx = tid + i * 256;
      int m = idx >> 2, kq = idx & 3;
      int gr = row0 + m;
      float4 a = make_float4(0.f, 0.f, 0.f, 0.f);
      if (gr < M) a = *(const float4*)(A + (size_t)gr * K + k0 + kq * 4);
      As[kq * 4 + 0][m] = a.x; As[kq * 4 + 1][m] = a.y;
      As[kq * 4 + 2][m] = a.z; As[kq * 4 + 3][m] = a.w;
    }
    {
      int n = tid >> 2, kq = tid & 3;
      float4 b = *(const float4*)(Bw + (size_t)n * K + k0 + kq * 4);
      Bs[kq * 4 + 0][n] = b.x; Bs[kq * 4 + 1][n] = b.y;
      Bs[kq * 4 + 2][n] = b.z; Bs[kq * 4 + 3][n] = b.w;
    }
    __syncthreads();
#pragma unroll
    for (int kk = 0; kk < BK; ++kk) {
      float av[8], bv[4];
      *(float4*)&av[0] = *(const float4*)&As[kk][ty * 8];
      *(float4*)&av[4] = *(const float4*)&As[kk][ty * 8 + 4];
      *(float4*)&bv[0] = *(const float4*)&Bs[kk][tx * 4];
#pragma unroll
      for (int i = 0; i < 8; ++i)
#pragma unroll
        for (int j = 0; j < 4; ++j) acc[i][j] = fmaf(av[i], bv[j], acc[i][j]);
    }
    __syncthreads();
  }

  float4 bb = *(const float4*)(bias + tx * 4);
#pragma unroll
  for (int i = 0; i < 8; ++i) {
    int m = row0 + ty * 8 + i;
    if (m < M) {
      float4 o;
      o.x = acc[i][0] + bb.x; o.y = acc[i][1] + bb.y;
      o.z = acc[i][2] + bb.z; o.w = acc[i][3] + bb.w;
      if (cold[m] > 0) o = *(const float4*)(mmf + (size_t)m * 64 + tx * 4);
      *(float4*)(C + (size_t)m * 64 + tx * 4) = o;
    }
  }
}

// ---------------- fused gather / l2 / LN / qkv / attention / mean ----------
__global__ __launch_bounds__(256) void attn_kernel(
    const int* __restrict__ seq, const float* __restrict__ mmf,
    const float* __restrict__ ie, const float* __restrict__ cf,
    const float* __restrict__ wq, const float* __restrict__ wk,
    const float* __restrict__ wv, float* __restrict__ out) {
  __shared__ float wql[64 * 64];   // transposed: [d][j]
  __shared__ float wkl[64 * 64];
  __shared__ float wvl[64 * 64];
  __shared__ float xnl[4][3][64];
  __shared__ float zl[4][64];
  const int tid = threadIdx.x;
  for (int idx = tid; idx < 4096; idx += 256) {
    int j = idx >> 6, d = idx & 63;
    wql[d * 64 + j] = wq[idx];
    wkl[d * 64 + j] = wk[idx];
    wvl[d * 64 + j] = wv[idx];
  }
  __syncthreads();
  const int w = tid >> 6, lane = tid & 63;
  const int rowBase = blockIdx.x * 16;

  for (int rr = 0; rr < 4; ++rr) {
    const int row = rowBase + rr * 4 + w;
    int sidx = seq[row];
    sidx = (sidx == NI) ? 0 : sidx;
    const size_t base = (size_t)sidx * 64 + lane;
    float fv[3];
    fv[0] = mmf[base]; fv[1] = ie[base]; fv[2] = cf[base];
    float xr[3];
#pragma unroll
    for (int t = 0; t < 3; ++t) {
      float v = fv[t];
      float s1 = v, s2 = v * v;
#pragma unroll
      for (int off = 32; off; off >>= 1) {
        s1 += __shfl_xor(s1, off);
        s2 += __shfl_xor(s2, off);
      }
      float inv = 1.0f / fmaxf(sqrtf(s2), 1e-12f);
      float x = v * inv;
      float mu = s1 * inv * 0.015625f;
      float var = fmaxf(s2 * inv * inv * 0.015625f - mu * mu, 0.0f);
      float rs = 1.0f / sqrtf(var + 1e-5f);
      float xn = (x - mu) * rs;
      xr[t] = xn;
      xnl[w][t][lane] = xn;
    }
    __syncthreads();

    float q0 = 0, q1 = 0, q2 = 0, k0 = 0, k1 = 0, k2 = 0;
#pragma unroll 4
    for (int d0 = 0; d0 < 64; d0 += 4) {
      float xa[4], xb[4], xc[4];
      *(float4*)xa = *(const float4*)&xnl[w][0][d0];
      *(float4*)xb = *(const float4*)&xnl[w][1][d0];
      *(float4*)xc = *(const float4*)&xnl[w][2][d0];
#pragma unroll
      for (int i = 0; i < 4; ++i) {
        const int d = d0 + i;
        float a = wql[d * 64 + lane];
        float b = wkl[d * 64 + lane];
        q0 = fmaf(xa[i], a, q0); q1 = fmaf(xb[i], a, q1); q2 = fmaf(xc[i], a, q2);
        k0 = fmaf(xa[i], b, k0); k1 = fmaf(xb[i], b, k1); k2 = fmaf(xc[i], b, k2);
      }
    }
    float qv[3] = {q0, q1, q2}, kv[3] = {k0, k1, k2};
    float lg[3][3];
#pragma unroll
    for (int a = 0; a < 3; ++a)
#pragma unroll
      for (int b = 0; b < 3; ++b) {
        float ss = qv[a] * kv[b];
#pragma unroll
        for (int off = 32; off; off >>= 1) ss += __shfl_xor(ss, off);
        lg[a][b] = ss * 0.125f;
      }
    float coef0 = 0, coef1 = 0, coef2 = 0;
#pragma unroll
    for (int a = 0; a < 3; ++a) {
      float mx = fmaxf(lg[a][0], fmaxf(lg[a][1], lg[a][2]));
      float e0 = expf(lg[a][0] - mx);
      float e1 = expf(lg[a][1] - mx);
      float e2 = expf(lg[a][2] - mx);
      float is = 1.0f / (e0 + e1 + e2);
      coef0 += e0 * is; coef1 += e1 * is; coef2 += e2 * is;
    }
    float z = (coef0 * xr[0] + coef1 * xr[1] + coef2 * xr[2]) * (1.0f / 3.0f);
    zl[w][lane] = z;
    __syncthreads();
    float y = 0.f;
#pragma unroll 4
    for (int d0 = 0; d0 < 64; d0 += 4) {
      float za[4];
      *(float4*)za = *(const float4*)&zl[w][d0];
#pragma unroll
      for (int i = 0; i < 4; ++i) y = fmaf(za[i], wvl[(d0 + i) * 64 + lane], y);
    }
    out[(size_t)row * 64 + lane] = y;
    __syncthreads();
  }
}

extern "C" void kernel_launch(void* const* d_in, const int* in_sizes, int n_in,
                              void* d_out, int out_size, void* d_ws, size_t ws_size,
                              hipStream_t stream) {
  const int*   seq     = (const int*)d_in[0];
  const int*   cold    = (const int*)d_in[1];
  const float* content = (const float*)d_in[2];
  const float* text    = (const float*)d_in[3];
  const float* cff     = (const float*)d_in[4];
  const float* iemb    = (const float*)d_in[5];
  const float* c_w1 = (const float*)d_in[6];
  const float* c_b1 = (const float*)d_in[7];
  const float* c_w2 = (const float*)d_in[8];
  const float* c_b2 = (const float*)d_in[9];
  const float* c_w3 = (const float*)d_in[10];
  const float* c_b3 = (const float*)d_in[11];
  const float* t_w1 = (const float*)d_in[12];
  const float* t_b1 = (const float*)d_in[13];
  const float* t_w2 = (const float*)d_in[14];
  const float* t_b2 = (const float*)d_in[15];
  const float* t_w3 = (const float*)d_in[16];
  const float* t_b3 = (const float*)d_in[17];
  const float* cf_w = (const float*)d_in[18];
  const float* cf_b = (const float*)d_in[19];
  const float* w_q  = (const float*)d_in[20];
  const float* w_k  = (const float*)d_in[21];
  const float* w_v  = (const float*)d_in[22];
  float* out = (float*)d_out;

  // ---- workspace layout (bytes) ----
  char* base = (char*)d_ws;
  f16* Wh   = (f16*)base;                         // 1,064,960 halves = 2,129,920 B
  f16* cw1h = Wh;                                 // 768*768
  f16* cw2h = Wh + 589824;                        // 256*768
  f16* cw3h = Wh + 786432;                        // 64*256
  f16* tw1h = Wh + 802816;                        // 384*384
  f16* tw2h = Wh + 950272;                        // 256*384
  f16* tw3h = Wh + 1048576;                       // 64*256 (ends 1,064,960)
  char* pA  = base + 2129920;                     // A_h region: 30,867,456 B
  f16* A_h  = (f16*)pA;
  float* C3c = (float*)(pA + 16000000);           // 5,144,576 B (content A dead)
  float* C3t = (float*)(pA + 21200000);           // 5,144,576 B
  f16* H1_h = (f16*)(base + 33000000);            // 30,867,456 B
  f16* H2_h = (f16*)(base + 63900000);            // 10,289,152 B
  float* mmf = (float*)(base + 74200000);         // 5,120,000 B
  float* cfo = (float*)(base + 79330000);         // 5,120,000 B  (ends ~84.5 MB)

  // weight conversions (fp16)
  cvt_kernel<<<(147456 + 255) / 256, 256, 0, stream>>>(c_w1, cw1h, 147456);
  cvt_kernel<<<(49152  + 255) / 256, 256, 0, stream>>>(c_w2, cw2h, 49152);
  cvt_kernel<<<(4096   + 255) / 256, 256, 0, stream>>>(c_w3, cw3h, 4096);
  cvt_kernel<<<(36864  + 255) / 256, 256, 0, stream>>>(t_w1, tw1h, 36864);
  cvt_kernel<<<(24576  + 255) / 256, 256, 0, stream>>>(t_w2, tw2h, 24576);
  cvt_kernel<<<(4096   + 255) / 256, 256, 0, stream>>>(t_w3, tw3h, 4096);

  // content encoder
  l2cvt_kernel<768><<<MPAD / 4, 256, 0, stream>>>(content, A_h);
  mgemm_kernel<768, 768, 1, 1><<<dim3(157, 12), 256, 0, stream>>>(A_h, cw1h, c_b1, H1_h);
  mgemm_kernel<768, 256, 1, 1><<<dim3(157, 4), 256, 0, stream>>>(H1_h, cw2h, c_b2, H2_h);
  mgemm_kernel<256, 64, 0, 0><<<dim3(157, 1), 256, 0, stream>>>(H2_h, cw3h, c_b3, C3c);

  // text encoder (reuses A_h / H1_h / H2_h)
  l2cvt_kernel<384><<<MPAD / 4, 256, 0, stream>>>(text, A_h);
  mgemm_kernel<384, 384, 1, 1><<<dim3(157, 6), 256, 0, stream>>>(A_h, tw1h, t_b1, H1_h);
  mgemm_kernel<384, 256, 1, 1><<<dim3(157, 4), 256, 0, stream>>>(H1_h, tw2h, t_b2, H2_h);
  mgemm_kernel<256, 64, 0, 0><<<dim3(157, 1), 256, 0, stream>>>(H2_h, tw3h, t_b3, C3t);

  // mm = l2(c3) + l2(t3)
  l2add_kernel<<<NI / 4, 256, 0, stream>>>(C3c, C3t, mmf);

  // cf linear + cold-item scatter (f32)
  gemm_cf_kernel<<<dim3(157), 256, 0, stream>>>(cff, cf_w, cf_b, cold, mmf, cfo, NI);

  // gather + l2 + LN + qkv + 3x3 attention + mean
  attn_kernel<<<3200, 256, 0, stream>>>(seq, mmf, iemb, cfo, w_q, w_k, w_v, out);
}